// Round 1
// baseline (120.466 us; speedup 1.0000x reference)
//
#include <hip/hip_runtime.h>
#include <math.h>

#define DCH  128    // channel dim
#define NPIX 4096   // H*W
#define BATCH 8

// ---------------------------------------------------------------------------
// Kernel 1: L2-normalize over channels, write transposed (B*N, D) layout.
// One thread per pixel. Reads coalesced (consecutive lanes = consecutive n).
// Writes float4 per lane (stride 512B between lanes; acceptable, write-once).
// ---------------------------------------------------------------------------
__global__ void stego_normalize(const float* __restrict__ feat,
                                float* __restrict__ fnorm, int BN) {
    int p = blockIdx.x * blockDim.x + threadIdx.x;
    if (p >= BN) return;
    int b = p / NPIX;
    int n = p - b * NPIX;
    const float* base = feat + (size_t)b * DCH * NPIX + n;

    float sum = 0.f;
#pragma unroll 8
    for (int d = 0; d < DCH; ++d) {
        float v = base[(size_t)d * NPIX];
        sum += v * v;
    }
    float inv = 1.0f / fmaxf(sqrtf(sum), 1e-12f);

    float4* outp = (float4*)(fnorm + (size_t)p * DCH);
#pragma unroll 4
    for (int d = 0; d < DCH; d += 4) {
        float4 v;
        v.x = base[(size_t)(d + 0) * NPIX] * inv;
        v.y = base[(size_t)(d + 1) * NPIX] * inv;
        v.z = base[(size_t)(d + 2) * NPIX] * inv;
        v.w = base[(size_t)(d + 3) * NPIX] * inv;
        outp[d >> 2] = v;
    }
}

// ---------------------------------------------------------------------------
// Kernel 2: one thread per pair; t < P -> positive (softplus(-s)),
// t >= P -> negative (softplus(+s)). Contiguous float4 gathers from fnorm.
// ---------------------------------------------------------------------------
__global__ void stego_pair_loss(const float* __restrict__ fnorm,
                                const int* __restrict__ pb, const int* __restrict__ pi,
                                const int* __restrict__ pj,
                                const int* __restrict__ nb, const int* __restrict__ ni,
                                const int* __restrict__ nj,
                                float* __restrict__ out, int P, float invP) {
    int t = blockIdx.x * blockDim.x + threadIdx.x;
    float loss = 0.f;
    if (t < 2 * P) {
        int b, i, j;
        float sgn;
        if (t < P) { b = pb[t]; i = pi[t]; j = pj[t]; sgn = -1.f; }
        else { int u = t - P; b = nb[u]; i = ni[u]; j = nj[u]; sgn = 1.f; }

        const float4* va = (const float4*)(fnorm + ((size_t)b * NPIX + i) * DCH);
        const float4* vb = (const float4*)(fnorm + ((size_t)b * NPIX + j) * DCH);
        float dot = 0.f;
#pragma unroll
        for (int k = 0; k < DCH / 4; ++k) {
            float4 a = va[k];
            float4 c = vb[k];
            dot += a.x * c.x + a.y * c.y + a.z * c.z + a.w * c.w;
        }
        float z = sgn * dot * 10.0f;                       // /TEMPERATURE, signed
        float sp = fmaxf(z, 0.f) + log1pf(expf(-fabsf(z))); // stable softplus
        loss = sp * invP;
    }
    // wave (64) shuffle reduction
    for (int off = 32; off > 0; off >>= 1)
        loss += __shfl_down(loss, off, 64);
    __shared__ float red[4];
    int lane = threadIdx.x & 63;
    int wave = threadIdx.x >> 6;
    if (lane == 0) red[wave] = loss;
    __syncthreads();
    if (threadIdx.x == 0) {
        float s = red[0] + red[1] + red[2] + red[3];
        atomicAdd(out, s);
    }
}

// ---------------------------------------------------------------------------
// Fallback (ws too small to hold fnorm): only store 1/norm per pixel and
// gather raw strided features in the pair kernel.
// ---------------------------------------------------------------------------
__global__ void stego_invnorm(const float* __restrict__ feat,
                              float* __restrict__ invn, int BN) {
    int p = blockIdx.x * blockDim.x + threadIdx.x;
    if (p >= BN) return;
    int b = p / NPIX;
    int n = p - b * NPIX;
    const float* base = feat + (size_t)b * DCH * NPIX + n;
    float sum = 0.f;
#pragma unroll 8
    for (int d = 0; d < DCH; ++d) {
        float v = base[(size_t)d * NPIX];
        sum += v * v;
    }
    invn[p] = 1.0f / fmaxf(sqrtf(sum), 1e-12f);
}

__global__ void stego_pair_loss_strided(const float* __restrict__ feat,
                                        const float* __restrict__ invn,
                                        const int* __restrict__ pb, const int* __restrict__ pi,
                                        const int* __restrict__ pj,
                                        const int* __restrict__ nb, const int* __restrict__ ni,
                                        const int* __restrict__ nj,
                                        float* __restrict__ out, int P, float invP) {
    int t = blockIdx.x * blockDim.x + threadIdx.x;
    float loss = 0.f;
    if (t < 2 * P) {
        int b, i, j;
        float sgn;
        if (t < P) { b = pb[t]; i = pi[t]; j = pj[t]; sgn = -1.f; }
        else { int u = t - P; b = nb[u]; i = ni[u]; j = nj[u]; sgn = 1.f; }
        const float* a = feat + (size_t)b * DCH * NPIX + i;
        const float* c = feat + (size_t)b * DCH * NPIX + j;
        float dot = 0.f;
#pragma unroll 8
        for (int d = 0; d < DCH; ++d)
            dot += a[(size_t)d * NPIX] * c[(size_t)d * NPIX];
        dot *= invn[b * NPIX + i] * invn[b * NPIX + j];
        float z = sgn * dot * 10.0f;
        float sp = fmaxf(z, 0.f) + log1pf(expf(-fabsf(z)));
        loss = sp * invP;
    }
    for (int off = 32; off > 0; off >>= 1)
        loss += __shfl_down(loss, off, 64);
    __shared__ float red[4];
    int lane = threadIdx.x & 63;
    int wave = threadIdx.x >> 6;
    if (lane == 0) red[wave] = loss;
    __syncthreads();
    if (threadIdx.x == 0) {
        float s = red[0] + red[1] + red[2] + red[3];
        atomicAdd(out, s);
    }
}

extern "C" void kernel_launch(void* const* d_in, const int* in_sizes, int n_in,
                              void* d_out, int out_size, void* d_ws, size_t ws_size,
                              hipStream_t stream) {
    const float* feat = (const float*)d_in[0];
    const int* pb = (const int*)d_in[1];
    const int* pi = (const int*)d_in[2];
    const int* pj = (const int*)d_in[3];
    const int* nb = (const int*)d_in[4];
    const int* ni = (const int*)d_in[5];
    const int* nj = (const int*)d_in[6];
    float* out = (float*)d_out;

    const int P = in_sizes[1];
    const int BN = BATCH * NPIX;
    const float invP = 1.0f / (float)P;

    hipMemsetAsync(d_out, 0, sizeof(float), stream);

    size_t need = (size_t)BN * DCH * sizeof(float);
    if (ws_size >= need) {
        float* fnorm = (float*)d_ws;
        stego_normalize<<<(BN + 255) / 256, 256, 0, stream>>>(feat, fnorm, BN);
        int total = 2 * P;
        stego_pair_loss<<<(total + 255) / 256, 256, 0, stream>>>(
            fnorm, pb, pi, pj, nb, ni, nj, out, P, invP);
    } else {
        float* invn = (float*)d_ws;  // BN floats = 128 KB
        stego_invnorm<<<(BN + 255) / 256, 256, 0, stream>>>(feat, invn, BN);
        int total = 2 * P;
        stego_pair_loss_strided<<<(total + 255) / 256, 256, 0, stream>>>(
            feat, invn, pb, pi, pj, nb, ni, nj, out, P, invP);
    }
}

// Round 2
// 101.422 us; speedup vs baseline: 1.1878x; 1.1878x over previous
//
#include <hip/hip_runtime.h>
#include <math.h>

#define DCH  128    // channel dim
#define NPIX 4096   // H*W
#define BATCH 8
#define BN   (BATCH * NPIX)
#define NPART_MAX 8192

// ---------------------------------------------------------------------------
// Kernel 1: L2-normalize over channels, write transposed (B*N, D) layout.
// 256-thread block = 64 pixels x 4 channel-quarters. One-pass: each thread
// holds its 32 channel values in VGPRs; sum-of-squares combined via LDS.
// 512 blocks -> 2 blocks/CU, 8 waves/CU.
// ---------------------------------------------------------------------------
__global__ void stego_normalize2(const float* __restrict__ feat,
                                 float* __restrict__ fnorm) {
    int lp = threadIdx.x & 63;        // pixel within block
    int q  = threadIdx.x >> 6;        // channel quarter 0..3
    int p  = blockIdx.x * 64 + lp;    // global pixel id (BN/64 = 512 blocks exact)
    int b  = p >> 12;                 // p / NPIX
    int n  = p & (NPIX - 1);
    const float* base = feat + ((size_t)b * DCH + q * 32) * NPIX + n;

    float vals[32];
    float s = 0.f;
#pragma unroll
    for (int d = 0; d < 32; ++d) {
        float v = base[(size_t)d * NPIX];   // lanes consecutive n -> coalesced
        vals[d] = v;
        s += v * v;
    }

    __shared__ float part[256];
    part[q * 64 + lp] = s;
    __syncthreads();
    float tot = part[lp] + part[64 + lp] + part[128 + lp] + part[192 + lp];
    float inv = 1.0f / fmaxf(sqrtf(tot), 1e-12f);

    float4* outp = (float4*)(fnorm + (size_t)p * DCH + q * 32);
#pragma unroll
    for (int k = 0; k < 8; ++k) {
        float4 v;
        v.x = vals[4 * k + 0] * inv;
        v.y = vals[4 * k + 1] * inv;
        v.z = vals[4 * k + 2] * inv;
        v.w = vals[4 * k + 3] * inv;
        outp[k] = v;
    }
}

// ---------------------------------------------------------------------------
// Kernel 2: 8 lanes per pair. Each lane loads 4 float4s at 128B stride from
// each vector -> per-iteration each pair covers a contiguous 128B segment.
// xor-shuffle reduce within the 8 lanes; per-block partial written to ws.
// ---------------------------------------------------------------------------
__global__ void stego_pair_loss2(const float* __restrict__ fnorm,
                                 const int* __restrict__ pb, const int* __restrict__ pi,
                                 const int* __restrict__ pj,
                                 const int* __restrict__ nb, const int* __restrict__ ni,
                                 const int* __restrict__ nj,
                                 float* __restrict__ partials, int P, float invP) {
    int t = blockIdx.x * blockDim.x + threadIdx.x;
    int pair = t >> 3;
    int sub  = t & 7;
    float dot = 0.f;
    float sgn = 1.f;
    bool active = (pair < 2 * P);
    if (active) {
        int b, i, j;
        if (pair < P) { b = pb[pair]; i = pi[pair]; j = pj[pair]; sgn = -1.f; }
        else { int u = pair - P; b = nb[u]; i = ni[u]; j = nj[u]; }
        const float4* va = (const float4*)(fnorm + ((size_t)b * NPIX + i) * DCH) + sub;
        const float4* vb = (const float4*)(fnorm + ((size_t)b * NPIX + j) * DCH) + sub;
#pragma unroll
        for (int k = 0; k < 4; ++k) {
            float4 a = va[8 * k];
            float4 c = vb[8 * k];
            dot += a.x * c.x + a.y * c.y + a.z * c.z + a.w * c.w;
        }
    }
    // reduce dot across the 8 lanes of this pair
    dot += __shfl_xor(dot, 4, 64);
    dot += __shfl_xor(dot, 2, 64);
    dot += __shfl_xor(dot, 1, 64);

    float loss = 0.f;
    if (active && sub == 0) {
        float z = sgn * dot * 10.0f;                        // /TEMPERATURE, signed
        loss = (fmaxf(z, 0.f) + log1pf(expf(-fabsf(z)))) * invP;  // stable softplus
    }
    // loss nonzero only on lanes 0,8,...,56 -> xor over bits 3..5 sums them
    loss += __shfl_xor(loss, 8, 64);
    loss += __shfl_xor(loss, 16, 64);
    loss += __shfl_xor(loss, 32, 64);

    __shared__ float red[4];
    int lane = threadIdx.x & 63;
    int wave = threadIdx.x >> 6;
    if (lane == 0) red[wave] = loss;
    __syncthreads();
    if (threadIdx.x == 0)
        partials[blockIdx.x] = red[0] + red[1] + red[2] + red[3];
}

// ---------------------------------------------------------------------------
// Kernel 3: final deterministic reduce of per-block partials -> d_out.
// ---------------------------------------------------------------------------
__global__ void stego_reduce(const float* __restrict__ partials,
                             float* __restrict__ out, int nPart) {
    float s = 0.f;
    for (int idx = threadIdx.x; idx < nPart; idx += blockDim.x)
        s += partials[idx];
    for (int off = 32; off > 0; off >>= 1)
        s += __shfl_down(s, off, 64);
    __shared__ float red[4];
    if ((threadIdx.x & 63) == 0) red[threadIdx.x >> 6] = s;
    __syncthreads();
    if (threadIdx.x == 0) out[0] = red[0] + red[1] + red[2] + red[3];
}

// ---------------------------------------------------------------------------
// Fallback (ws too small): invnorm-only + strided gathers + atomics.
// ---------------------------------------------------------------------------
__global__ void stego_invnorm(const float* __restrict__ feat,
                              float* __restrict__ invn, int bn) {
    int p = blockIdx.x * blockDim.x + threadIdx.x;
    if (p >= bn) return;
    int b = p / NPIX;
    int n = p - b * NPIX;
    const float* base = feat + (size_t)b * DCH * NPIX + n;
    float sum = 0.f;
#pragma unroll 8
    for (int d = 0; d < DCH; ++d) {
        float v = base[(size_t)d * NPIX];
        sum += v * v;
    }
    invn[p] = 1.0f / fmaxf(sqrtf(sum), 1e-12f);
}

__global__ void stego_pair_loss_strided(const float* __restrict__ feat,
                                        const float* __restrict__ invn,
                                        const int* __restrict__ pb, const int* __restrict__ pi,
                                        const int* __restrict__ pj,
                                        const int* __restrict__ nb, const int* __restrict__ ni,
                                        const int* __restrict__ nj,
                                        float* __restrict__ out, int P, float invP) {
    int t = blockIdx.x * blockDim.x + threadIdx.x;
    float loss = 0.f;
    if (t < 2 * P) {
        int b, i, j;
        float sgn;
        if (t < P) { b = pb[t]; i = pi[t]; j = pj[t]; sgn = -1.f; }
        else { int u = t - P; b = nb[u]; i = ni[u]; j = nj[u]; sgn = 1.f; }
        const float* a = feat + (size_t)b * DCH * NPIX + i;
        const float* c = feat + (size_t)b * DCH * NPIX + j;
        float dot = 0.f;
#pragma unroll 8
        for (int d = 0; d < DCH; ++d)
            dot += a[(size_t)d * NPIX] * c[(size_t)d * NPIX];
        dot *= invn[b * NPIX + i] * invn[b * NPIX + j];
        float z = sgn * dot * 10.0f;
        float sp = fmaxf(z, 0.f) + log1pf(expf(-fabsf(z)));
        loss = sp * invP;
    }
    for (int off = 32; off > 0; off >>= 1)
        loss += __shfl_down(loss, off, 64);
    __shared__ float red[4];
    int lane = threadIdx.x & 63;
    int wave = threadIdx.x >> 6;
    if (lane == 0) red[wave] = loss;
    __syncthreads();
    if (threadIdx.x == 0) {
        float s = red[0] + red[1] + red[2] + red[3];
        atomicAdd(out, s);
    }
}

extern "C" void kernel_launch(void* const* d_in, const int* in_sizes, int n_in,
                              void* d_out, int out_size, void* d_ws, size_t ws_size,
                              hipStream_t stream) {
    const float* feat = (const float*)d_in[0];
    const int* pb = (const int*)d_in[1];
    const int* pi = (const int*)d_in[2];
    const int* pj = (const int*)d_in[3];
    const int* nb = (const int*)d_in[4];
    const int* ni = (const int*)d_in[5];
    const int* nj = (const int*)d_in[6];
    float* out = (float*)d_out;

    const int P = in_sizes[1];
    const float invP = 1.0f / (float)P;

    size_t fnorm_bytes = (size_t)BN * DCH * sizeof(float);
    int pairThreads = 2 * P * 8;
    int pairBlocks = (pairThreads + 255) / 256;   // 8192 for P=65536
    size_t need = fnorm_bytes + (size_t)pairBlocks * sizeof(float);

    if (ws_size >= need && pairBlocks <= NPART_MAX) {
        float* fnorm = (float*)d_ws;
        float* partials = (float*)((char*)d_ws + fnorm_bytes);
        stego_normalize2<<<BN / 64, 256, 0, stream>>>(feat, fnorm);
        stego_pair_loss2<<<pairBlocks, 256, 0, stream>>>(
            fnorm, pb, pi, pj, nb, ni, nj, partials, P, invP);
        stego_reduce<<<1, 256, 0, stream>>>(partials, out, pairBlocks);
    } else {
        hipMemsetAsync(d_out, 0, sizeof(float), stream);
        float* invn = (float*)d_ws;  // BN floats = 128 KB
        stego_invnorm<<<(BN + 255) / 256, 256, 0, stream>>>(feat, invn, BN);
        int total = 2 * P;
        stego_pair_loss_strided<<<(total + 255) / 256, 256, 0, stream>>>(
            feat, invn, pb, pi, pj, nb, ni, nj, out, P, invP);
    }
}